// Round 5
// baseline (8700.011 us; speedup 1.0000x reference)
//
#include <hip/hip_runtime.h>
#include <hip/hip_cooperative_groups.h>

// LSTM: B=1024, T=128, I=128, H=1024, O=64
// R4: persistent cooperative kernel, spill fixed.
//  - R3 failed because __launch_bounds__(512,2) capped VGPR at 128 (2nd arg
//    acts like CUDA min-blocks/CU: 2 blocks -> 4 waves/EU -> 512/4=128), so
//    the 144-reg Breg array spilled to scratch (4.2 GB FETCH/dispatch).
//  - Now: __launch_bounds__(512,1) (cap >=256) AND Breg trimmed to 128 regs
//    (W_hh only, K=1024). W_ih (x-part, K=128) lives in a 32 KB LDS image
//    per block, R2's conflict-free XOR-swizzled layout, loaded once.
// Carried: dbuf A-staging via global_load_lds(16B), in-wave shfl gate
// gather, grid.sync between steps, MFMA proj with hi/lo bf16 w_fc.

#define B_DIM 1024
#define H_DIM 1024
#define I_DIM 128
#define T_DIM 128
#define XROW  (T_DIM * I_DIM)   // 16384
#define NCHUNK 36               // total K chunks of 32 (x: 0..3, h: 4..35)
#define O_DIM 64

typedef float f32x4 __attribute__((ext_vector_type(4)));
typedef short bf16x8 __attribute__((ext_vector_type(8)));
typedef unsigned short u16x8 __attribute__((ext_vector_type(8)));

__device__ __forceinline__ unsigned short f2bf(float f) {
    union { float f; unsigned int u; } v; v.f = f;
    unsigned int r = v.u + 0x7fffu + ((v.u >> 16) & 1u);  // RNE
    return (unsigned short)(r >> 16);
}
__device__ __forceinline__ float bf2f(unsigned short b) {
    union { unsigned int u; float f; } v; v.u = ((unsigned int)b) << 16;
    return v.f;
}
__device__ __forceinline__ float sigm(float x) { return 1.f / (1.f + __expf(-x)); }
__device__ __forceinline__ float tanh_fast(float x) { return 2.f / (1.f + __expf(-2.f * x)) - 1.f; }

// ---- prep: fp32 x -> bf16 ----
__global__ void conv_x(const float* __restrict__ x, unsigned short* __restrict__ xb) {
    size_t i = ((size_t)blockIdx.x * 256 + threadIdx.x) * 8;
    float4 v0 = *(const float4*)(x + i);
    float4 v1 = *(const float4*)(x + i + 4);
    u16x8 o;
    o[0] = f2bf(v0.x); o[1] = f2bf(v0.y); o[2] = f2bf(v0.z); o[3] = f2bf(v0.w);
    o[4] = f2bf(v1.x); o[5] = f2bf(v1.y); o[6] = f2bf(v1.z); o[7] = f2bf(v1.w);
    *(u16x8*)(xb + i) = o;
}

// ---- prep: W2 in B-fragment order + combined bias ----
// N-order n: nb=n>>7, wn=(n>>4)&7, gate=(n>>2)&3, ju=n&3
//   -> orig gate row = gate*1024 + nb*32 + wn*4 + ju
// W2 element (chunk c, n, q, j) = Worig[orig(n)][c*32 + q*8 + j]
__global__ void build_w2(const float* __restrict__ w_ih, const float* __restrict__ w_hh,
                         const float* __restrict__ b_ih, const float* __restrict__ b_hh,
                         unsigned short* __restrict__ W2, float* __restrict__ bias2) {
    int n = blockIdx.x;
    int nb = n >> 7, wn = (n >> 4) & 7, gate = (n >> 2) & 3, ju = n & 3;
    int orig = gate * 1024 + nb * 32 + wn * 4 + ju;
    for (int k = threadIdx.x; k < 1152; k += 256) {
        float v = (k < I_DIM) ? w_ih[(size_t)orig * I_DIM + k]
                              : w_hh[(size_t)orig * H_DIM + (k - I_DIM)];
        int cch = k >> 5, q = (k >> 3) & 3, j = k & 7;
        W2[(size_t)cch * 131072 + (size_t)n * 32 + q * 8 + j] = f2bf(v);
    }
    if (threadIdx.x == 0) bias2[n] = b_ih[orig] + b_hh[orig];
}

// ---- prep: W_ih LDS image per nb-block, R2-Bs swizzled layout ----
// image[nb][half][col][64] : at (col, phys group g) holds logical group
// g^(col&7) of K-half `half`, i.e. k = half*64 + (g^(col&7))*8 + j.
__global__ void build_wih(const float* __restrict__ w_ih,
                          unsigned short* __restrict__ Wihg) {
    int n = blockIdx.x;              // 0..4095 (N-order)
    int nb = n >> 7, col = n & 127;
    int wn = col >> 4, gate = (col >> 2) & 3, ju = col & 3;
    int orig = gate * 1024 + nb * 32 + wn * 4 + ju;
    int k = threadIdx.x;             // 0..127
    int half = k >> 6, kl = k & 63;
    int glog = kl >> 3, j = kl & 7;
    int gphys = glog ^ (col & 7);
    Wihg[(((size_t)nb * 2 + half) * 128 + col) * 64 + gphys * 8 + j] =
        f2bf(w_ih[(size_t)orig * I_DIM + k]);
}

// ---- prep: w_fc fp32 -> hi/lo bf16 pair ----
__global__ void conv_wfc(const float* __restrict__ w_fc,
                         unsigned short* __restrict__ whi,
                         unsigned short* __restrict__ wlo) {
    int i = blockIdx.x * 256 + threadIdx.x;
    float v = w_fc[i];
    unsigned short h = f2bf(v);
    whi[i] = h;
    wlo[i] = f2bf(v - bf2f(h));
}

__global__ void zero_hc(unsigned short* __restrict__ h0, float* __restrict__ c) {
    int idx = blockIdx.x * 256 + threadIdx.x;
    h0[idx] = 0;
    c[idx] = 0.f;
}

// ---- persistent LSTM: all 128 timesteps in one cooperative kernel ----
// grid (32 nb, 8 mb) x 512 threads = 8 waves; 1 block/CU.
// Wave wv owns N-cols nb*128+wv*16..+15 for all M=128 rows of the block.
// W_hh B-fragments (32 chunks x 4 VGPR = 128 regs) persist in registers.
// W_ih B-fragments read from a 32 KB LDS image (loaded once).
__global__ __launch_bounds__(512, 1)
void lstm_persist(const unsigned short* __restrict__ xb,
                  const unsigned short* __restrict__ W2,
                  const unsigned short* __restrict__ Wihg,
                  const float* __restrict__ bias2,
                  unsigned short* __restrict__ h0,
                  unsigned short* __restrict__ h1,
                  float* __restrict__ c_st) {
    __shared__ __align__(16) unsigned short As[2 * 2 * 128 * 64];  // 64 KB
    __shared__ __align__(16) unsigned short Wih[2 * 128 * 64];     // 32 KB
    const int tid  = threadIdx.x;
    const int wv   = tid >> 6, lane = tid & 63;
    const int quad = lane >> 4, l16 = lane & 15;
    const int l7   = l16 & 7;
    const int nb   = blockIdx.x, mb = blockIdx.y;

    // one-time: W_ih image -> LDS (layouts identical, lane-linear copy)
#pragma unroll
    for (int i = 0; i < 4; ++i) {
        const unsigned short* src = Wihg + (size_t)nb * 16384 + (wv * 4 + i) * 512 + lane * 8;
        __builtin_amdgcn_global_load_lds(
            (const __attribute__((address_space(1))) void*)src,
            (__attribute__((address_space(3))) void*)(&Wih[(wv * 4 + i) * 512]),
            16, 0, 0);
    }

    // one-time: W_hh B-fragments (K chunks 4..35) -> 128 VGPRs
    bf16x8 Breg[32];
    {
        const size_t nbase = (size_t)(nb * 128 + wv * 16 + l16) * 32 + quad * 8;
#pragma unroll
        for (int cch = 0; cch < 32; ++cch)
            Breg[cch] = *(const bf16x8*)&W2[(size_t)(cch + 4) * 131072 + nbase];
    }
    const float bn = bias2[nb * 128 + wv * 16 + l16];

    // staging lane geometry
    const int arow = lane >> 3;             // 0..7 local row
    const int ag   = lane & 7;              // physical 16B group
    const int cperm = ((ag ^ arow) << 3);   // swizzled source col (bf16 units)

    // epilogue lane geometry (active lanes l16<4)
    const int unit = nb * 32 + wv * 4 + (l16 & 3);
    // W_ih B-frag address base (col = wv*16 + l16)
    const int wihcol = wv * 16 + l16;

    cooperative_groups::grid_group grid = cooperative_groups::this_grid();

    for (int t = 0; t < T_DIM; ++t) {
        const unsigned short* hin = (t & 1) ? h1 : h0;
        unsigned short* hout      = (t & 1) ? h0 : h1;

        f32x4 acc[8];
#pragma unroll
        for (int mi = 0; mi < 8; ++mi) acc[mi] = f32x4{0.f, 0.f, 0.f, 0.f};

        // stage seg 0 (x_t) into buf 0
#pragma unroll
        for (int c4 = 0; c4 < 2; ++c4) {
#pragma unroll
            for (int hf = 0; hf < 2; ++hf) {
                const int row0 = wv * 16 + c4 * 8;
                const unsigned short* src =
                    xb + (size_t)(mb * 128 + row0 + arow) * XROW + t * I_DIM + hf * 64 + cperm;
                __builtin_amdgcn_global_load_lds(
                    (const __attribute__((address_space(1))) void*)src,
                    (__attribute__((address_space(3))) void*)(&As[((0 * 2 + hf) * 128 + row0) * 64]),
                    16, 0, 0);
            }
        }

#pragma unroll
        for (int s = 0; s < 9; ++s) {
            __syncthreads();  // stage(s) resident (barrier drains vmcnt)
            if (s < 8) {      // prefetch seg s+1 (h cols s*128..) into other buf
                const int nbuf = (s + 1) & 1;
#pragma unroll
                for (int c4 = 0; c4 < 2; ++c4) {
#pragma unroll
                    for (int hf = 0; hf < 2; ++hf) {
                        const int row0 = wv * 16 + c4 * 8;
                        const unsigned short* src =
                            hin + (size_t)(mb * 128 + row0 + arow) * H_DIM + s * 128 + hf * 64 + cperm;
                        __builtin_amdgcn_global_load_lds(
                            (const __attribute__((address_space(1))) void*)src,
                            (__attribute__((address_space(3))) void*)(&As[((nbuf * 2 + hf) * 128 + row0) * 64]),
                            16, 0, 0);
                    }
                }
            }
            const int bufc = s & 1;
#pragma unroll
            for (int cc = 0; cc < 4; ++cc) {
                const int half = cc >> 1, gb = (cc & 1) * 4;
                const int poff = (((gb + quad) ^ l7) << 3);
                bf16x8 bfrag;
                if (s == 0) {
                    bfrag = *(const bf16x8*)&Wih[(half * 128 + wihcol) * 64 + poff];
                } else {
                    bfrag = Breg[(s - 1) * 4 + cc];
                }
#pragma unroll
                for (int mi = 0; mi < 8; ++mi) {
                    const int row = mi * 16 + l16;
                    bf16x8 a = *(const bf16x8*)&As[((bufc * 2 + half) * 128 + row) * 64 + poff];
                    acc[mi] = __builtin_amdgcn_mfma_f32_16x16x32_bf16(a, bfrag, acc[mi], 0, 0, 0);
                }
            }
        }

        // epilogue: gather 4 gates (gate = l16>>2) via shfl_xor, cell update
#pragma unroll
        for (int mi = 0; mi < 8; ++mi) {
#pragma unroll
            for (int r = 0; r < 4; ++r) {
                float v  = acc[mi][r] + bn;
                float vf = __shfl_xor(v, 4);
                float vg = __shfl_xor(v, 8);
                float vo = __shfl_xor(v, 12);
                if (l16 < 4) {
                    const int row = mb * 128 + mi * 16 + quad * 4 + r;
                    const size_t idx = (size_t)row * H_DIM + unit;
                    const float cn = sigm(vf) * c_st[idx] + sigm(v) * tanh_fast(vg);
                    c_st[idx] = cn;
                    hout[idx] = f2bf(sigm(vo) * tanh_fast(cn));
                }
            }
        }

        grid.sync();  // h(t) visible device-wide before step t+1
    }
}

// ---- final projection via MFMA (hi/lo split w_fc) ----
__global__ __launch_bounds__(256, 1)
void proj_mfma(const unsigned short* __restrict__ h,
               const unsigned short* __restrict__ whi,
               const unsigned short* __restrict__ wlo,
               const float* __restrict__ b_fc,
               float* __restrict__ out) {
    const int wm = threadIdx.x >> 6, lane = threadIdx.x & 63;
    const int quad = lane >> 4, l16 = lane & 15;
    const int m0 = blockIdx.x * 64 + wm * 16;

    f32x4 acc[4];
#pragma unroll
    for (int ni = 0; ni < 4; ni++) acc[ni] = f32x4{0.f, 0.f, 0.f, 0.f};

    for (int k0 = 0; k0 < H_DIM; k0 += 32) {
        bf16x8 a = *(const bf16x8*)&h[(size_t)(m0 + l16) * H_DIM + k0 + quad * 8];
#pragma unroll
        for (int ni = 0; ni < 4; ni++) {
            const size_t wi = (size_t)(ni * 16 + l16) * H_DIM + k0 + quad * 8;
            bf16x8 bh = *(const bf16x8*)&whi[wi];
            bf16x8 bl = *(const bf16x8*)&wlo[wi];
            acc[ni] = __builtin_amdgcn_mfma_f32_16x16x32_bf16(a, bh, acc[ni], 0, 0, 0);
            acc[ni] = __builtin_amdgcn_mfma_f32_16x16x32_bf16(a, bl, acc[ni], 0, 0, 0);
        }
    }
#pragma unroll
    for (int ni = 0; ni < 4; ni++) {
        const float bfc = b_fc[ni * 16 + l16];
#pragma unroll
        for (int r = 0; r < 4; r++) {
            out[(size_t)(m0 + quad * 4 + r) * O_DIM + ni * 16 + l16] = acc[ni][r] + bfc;
        }
    }
}

extern "C" void kernel_launch(void* const* d_in, const int* in_sizes, int n_in,
                              void* d_out, int out_size, void* d_ws, size_t ws_size,
                              hipStream_t stream) {
    const float* x    = (const float*)d_in[0];
    const float* w_ih = (const float*)d_in[1];
    const float* w_hh = (const float*)d_in[2];
    const float* b_ih = (const float*)d_in[3];
    const float* b_hh = (const float*)d_in[4];
    const float* w_fc = (const float*)d_in[5];
    const float* b_fc = (const float*)d_in[6];
    float* out = (float*)d_out;

    char* ws = (char*)d_ws;
    size_t off = 0;
    unsigned short* xb   = (unsigned short*)(ws + off); off += (size_t)B_DIM * XROW * 2;
    unsigned short* W2   = (unsigned short*)(ws + off); off += (size_t)NCHUNK * 131072 * 2;
    unsigned short* Wihg = (unsigned short*)(ws + off); off += (size_t)32 * 16384 * 2;
    float* bias2         = (float*)(ws + off);          off += (size_t)4 * H_DIM * 4;
    unsigned short* h0   = (unsigned short*)(ws + off); off += (size_t)B_DIM * H_DIM * 2;
    unsigned short* h1   = (unsigned short*)(ws + off); off += (size_t)B_DIM * H_DIM * 2;
    float* c             = (float*)(ws + off);          off += (size_t)B_DIM * H_DIM * 4;
    unsigned short* whi  = (unsigned short*)(ws + off); off += (size_t)O_DIM * H_DIM * 2;
    unsigned short* wlo  = (unsigned short*)(ws + off); off += (size_t)O_DIM * H_DIM * 2;

    conv_x<<<8192, 256, 0, stream>>>(x, xb);
    build_w2<<<4 * H_DIM, 256, 0, stream>>>(w_ih, w_hh, b_ih, b_hh, W2, bias2);
    build_wih<<<4 * H_DIM, 128, 0, stream>>>(w_ih, Wihg);
    conv_wfc<<<256, 256, 0, stream>>>(w_fc, whi, wlo);
    zero_hc<<<4096, 256, 0, stream>>>(h0, c);

    void* args[] = {(void*)&xb, (void*)&W2, (void*)&Wihg, (void*)&bias2,
                    (void*)&h0, (void*)&h1, (void*)&c};
    hipLaunchCooperativeKernel((void*)lstm_persist, dim3(32, 8), dim3(512),
                               args, 0, stream);

    // t=127 wrote h0
    proj_mfma<<<16, 256, 0, stream>>>(h0, whi, wlo, b_fc, out);
}

// Round 6
// 6719.033 us; speedup vs baseline: 1.2948x; 1.2948x over previous
//
#include <hip/hip_runtime.h>
#include <hip/hip_cooperative_groups.h>

// LSTM: B=1024, T=128, I=128, H=1024, O=64
// R5: persistent kernel, grid.sync REPLACED by per-mb 32-block flag barrier.
//  - R3/R4 post-mortem: grid.sync's device-scope fences invalidated L2 on
//    every XCD every step -> 4 GB HBM refetch + ~67us/step. Not a spill
//    (VGPR=128 is arch half; Breg lives in AGPRs, legal MFMA B-operand).
//  - Now: blocks (nb, mb) only exchange h within their mb-group (32 blocks).
//    Producer: __threadfence + release atomicAdd on cnt[t][mb].
//    Consumer: acquire spin until 32, once per step, tid0 only.
//  - Grid (mb=8, nb=32): linear id % 8 == mb -> under round-robin dispatch
//    each mb-group sits on ONE XCD -> h exchange stays in that XCD's L2.
//    (Locality only; fences are device-scope so correctness is mapping-free.)
//  - c state moved to LDS (16 KB, block-private) -> survives fences, 0 traffic.
// Carried: W_hh in 128 regs (AGPR-friendly), W_ih in 32 KB LDS image,
// dbuf A-staging via global_load_lds(16B) w/ XOR swizzle, shfl gate gather,
// MFMA proj with hi/lo bf16 w_fc.

#define B_DIM 1024
#define H_DIM 1024
#define I_DIM 128
#define T_DIM 128
#define XROW  (T_DIM * I_DIM)   // 16384
#define NCHUNK 36               // total K chunks of 32 (x: 0..3, h: 4..35)
#define O_DIM 64

typedef float f32x4 __attribute__((ext_vector_type(4)));
typedef short bf16x8 __attribute__((ext_vector_type(8)));
typedef unsigned short u16x8 __attribute__((ext_vector_type(8)));

__device__ __forceinline__ unsigned short f2bf(float f) {
    union { float f; unsigned int u; } v; v.f = f;
    unsigned int r = v.u + 0x7fffu + ((v.u >> 16) & 1u);  // RNE
    return (unsigned short)(r >> 16);
}
__device__ __forceinline__ float bf2f(unsigned short b) {
    union { unsigned int u; float f; } v; v.u = ((unsigned int)b) << 16;
    return v.f;
}
__device__ __forceinline__ float sigm(float x) { return 1.f / (1.f + __expf(-x)); }
__device__ __forceinline__ float tanh_fast(float x) { return 2.f / (1.f + __expf(-2.f * x)) - 1.f; }

// ---- prep: fp32 x -> bf16 ----
__global__ void conv_x(const float* __restrict__ x, unsigned short* __restrict__ xb) {
    size_t i = ((size_t)blockIdx.x * 256 + threadIdx.x) * 8;
    float4 v0 = *(const float4*)(x + i);
    float4 v1 = *(const float4*)(x + i + 4);
    u16x8 o;
    o[0] = f2bf(v0.x); o[1] = f2bf(v0.y); o[2] = f2bf(v0.z); o[3] = f2bf(v0.w);
    o[4] = f2bf(v1.x); o[5] = f2bf(v1.y); o[6] = f2bf(v1.z); o[7] = f2bf(v1.w);
    *(u16x8*)(xb + i) = o;
}

// ---- prep: W2 in B-fragment order + combined bias ----
// N-order n: nb=n>>7, wn=(n>>4)&7, gate=(n>>2)&3, ju=n&3
//   -> orig gate row = gate*1024 + nb*32 + wn*4 + ju
__global__ void build_w2(const float* __restrict__ w_ih, const float* __restrict__ w_hh,
                         const float* __restrict__ b_ih, const float* __restrict__ b_hh,
                         unsigned short* __restrict__ W2, float* __restrict__ bias2) {
    int n = blockIdx.x;
    int nb = n >> 7, wn = (n >> 4) & 7, gate = (n >> 2) & 3, ju = n & 3;
    int orig = gate * 1024 + nb * 32 + wn * 4 + ju;
    for (int k = threadIdx.x; k < 1152; k += 256) {
        float v = (k < I_DIM) ? w_ih[(size_t)orig * I_DIM + k]
                              : w_hh[(size_t)orig * H_DIM + (k - I_DIM)];
        int cch = k >> 5, q = (k >> 3) & 3, j = k & 7;
        W2[(size_t)cch * 131072 + (size_t)n * 32 + q * 8 + j] = f2bf(v);
    }
    if (threadIdx.x == 0) bias2[n] = b_ih[orig] + b_hh[orig];
}

// ---- prep: W_ih LDS image per nb, swizzled (phys grp g holds logical g^(col&7)) ----
__global__ void build_wih(const float* __restrict__ w_ih,
                          unsigned short* __restrict__ Wihg) {
    int n = blockIdx.x;              // 0..4095 (N-order)
    int nb = n >> 7, col = n & 127;
    int wn = col >> 4, gate = (col >> 2) & 3, ju = col & 3;
    int orig = gate * 1024 + nb * 32 + wn * 4 + ju;
    int k = threadIdx.x;             // 0..127
    int half = k >> 6, kl = k & 63;
    int glog = kl >> 3, j = kl & 7;
    int gphys = glog ^ (col & 7);
    Wihg[(((size_t)nb * 2 + half) * 128 + col) * 64 + gphys * 8 + j] =
        f2bf(w_ih[(size_t)orig * I_DIM + k]);
}

// ---- prep: w_fc fp32 -> hi/lo bf16 pair ----
__global__ void conv_wfc(const float* __restrict__ w_fc,
                         unsigned short* __restrict__ whi,
                         unsigned short* __restrict__ wlo) {
    int i = blockIdx.x * 256 + threadIdx.x;
    float v = w_fc[i];
    unsigned short h = f2bf(v);
    whi[i] = h;
    wlo[i] = f2bf(v - bf2f(h));
}

__global__ void zero_hcnt(unsigned short* __restrict__ h0, unsigned int* __restrict__ cnt) {
    int idx = blockIdx.x * 256 + threadIdx.x;   // 4096 blocks -> 1048576
    h0[idx] = 0;
    if (idx < T_DIM * 8) cnt[idx] = 0;
}

// ---- persistent LSTM ----
// grid (8 mb, 32 nb) x 512 threads; 1 block/CU; mb-group = 32 blocks/XCD.
__global__ __launch_bounds__(512, 1)
void lstm_persist(const unsigned short* __restrict__ xb,
                  const unsigned short* __restrict__ W2,
                  const unsigned short* __restrict__ Wihg,
                  const float* __restrict__ bias2,
                  unsigned short* __restrict__ h0,
                  unsigned short* __restrict__ h1,
                  unsigned int* __restrict__ cnt) {
    __shared__ __align__(16) unsigned short As[2 * 2 * 128 * 64];  // 64 KB
    __shared__ __align__(16) unsigned short Wih[2 * 128 * 64];     // 32 KB
    __shared__ float c_lds[128 * 32];                              // 16 KB
    const int tid  = threadIdx.x;
    const int wv   = tid >> 6, lane = tid & 63;
    const int quad = lane >> 4, l16 = lane & 15;
    const int l7   = l16 & 7;
    const int mb   = blockIdx.x, nb = blockIdx.y;

    // zero block-private c state
    for (int i = tid; i < 128 * 32; i += 512) c_lds[i] = 0.f;

    // one-time: W_ih image -> LDS
#pragma unroll
    for (int i = 0; i < 4; ++i) {
        const unsigned short* src = Wihg + (size_t)nb * 16384 + (wv * 4 + i) * 512 + lane * 8;
        __builtin_amdgcn_global_load_lds(
            (const __attribute__((address_space(1))) void*)src,
            (__attribute__((address_space(3))) void*)(&Wih[(wv * 4 + i) * 512]),
            16, 0, 0);
    }

    // one-time: W_hh B-fragments (K chunks 4..35) -> 128 regs (VGPR or AGPR)
    bf16x8 Breg[32];
    {
        const size_t nbase = (size_t)(nb * 128 + wv * 16 + l16) * 32 + quad * 8;
#pragma unroll
        for (int cch = 0; cch < 32; ++cch)
            Breg[cch] = *(const bf16x8*)&W2[(size_t)(cch + 4) * 131072 + nbase];
    }
    const float bn = bias2[nb * 128 + wv * 16 + l16];

    // staging lane geometry
    const int arow = lane >> 3;             // 0..7 local row
    const int ag   = lane & 7;              // physical 16B group
    const int cperm = ((ag ^ arow) << 3);   // swizzled source col (bf16 units)

    const int unit   = nb * 32 + wv * 4 + (l16 & 3);   // global h-unit (epilogue)
    const int ccol   = wv * 4 + (l16 & 3);             // c_lds col
    const int wihcol = wv * 16 + l16;

#define STAGE_A(SRCBASE, ROWSTRIDE, COLOFF, BUF)                                   \
    do {                                                                           \
        _Pragma("unroll")                                                          \
        for (int c4 = 0; c4 < 2; ++c4) {                                           \
            _Pragma("unroll")                                                      \
            for (int hf = 0; hf < 2; ++hf) {                                       \
                const int row0 = wv * 16 + c4 * 8;                                 \
                const unsigned short* src =                                        \
                    (SRCBASE) + (size_t)(mb * 128 + row0 + arow) * (ROWSTRIDE)     \
                              + (COLOFF) + hf * 64 + cperm;                        \
                __builtin_amdgcn_global_load_lds(                                  \
                    (const __attribute__((address_space(1))) void*)src,            \
                    (__attribute__((address_space(3))) void*)                      \
                        (&As[(((BUF) * 2 + hf) * 128 + row0) * 64]),               \
                    16, 0, 0);                                                     \
            }                                                                      \
        }                                                                          \
    } while (0)

    for (int t = 0; t < T_DIM; ++t) {
        const unsigned short* hin = (t & 1) ? h1 : h0;
        unsigned short* hout      = (t & 1) ? h0 : h1;

        f32x4 acc[8];
#pragma unroll
        for (int mi = 0; mi < 8; ++mi) acc[mi] = f32x4{0.f, 0.f, 0.f, 0.f};

        // stage seg0 (x_t) into buf0; overlap with the group-barrier spin
        STAGE_A(xb, XROW, t * I_DIM, 0);
        if (t > 0 && tid == 0) {
            while (__hip_atomic_load(&cnt[(t - 1) * 8 + mb],
                                     __ATOMIC_ACQUIRE, __HIP_MEMORY_SCOPE_AGENT) < 32u)
                __builtin_amdgcn_s_sleep(1);
            __threadfence();   // acquire: invalidate stale h lines
        }
        __syncthreads();       // seg0 resident + spin done + Wih (t==0)

        // seg 0: B-fragments from Wih LDS; prefetch seg1
        STAGE_A(hin, H_DIM, 0, 1);
#pragma unroll
        for (int cc = 0; cc < 4; ++cc) {
            const int half = cc >> 1, gb = (cc & 1) * 4;
            const int poff = (((gb + quad) ^ l7) << 3);
            bf16x8 bfrag = *(const bf16x8*)&Wih[(half * 128 + wihcol) * 64 + poff];
#pragma unroll
            for (int mi = 0; mi < 8; ++mi) {
                bf16x8 a = *(const bf16x8*)&As[((0 * 2 + half) * 128 + mi * 16 + l16) * 64 + poff];
                acc[mi] = __builtin_amdgcn_mfma_f32_16x16x32_bf16(a, bfrag, acc[mi], 0, 0, 0);
            }
        }
        __syncthreads();

        // segs 1..8: B-fragments from Breg
#pragma unroll
        for (int sg = 1; sg <= 8; ++sg) {
            if (sg < 8) STAGE_A(hin, H_DIM, sg * 128, (sg + 1) & 1);
            const int bufc = sg & 1;
#pragma unroll
            for (int cc = 0; cc < 4; ++cc) {
                const int half = cc >> 1, gb = (cc & 1) * 4;
                const int poff = (((gb + quad) ^ l7) << 3);
                bf16x8 bfrag = Breg[(sg - 1) * 4 + cc];
#pragma unroll
                for (int mi = 0; mi < 8; ++mi) {
                    bf16x8 a = *(const bf16x8*)&As[((bufc * 2 + half) * 128 + mi * 16 + l16) * 64 + poff];
                    acc[mi] = __builtin_amdgcn_mfma_f32_16x16x32_bf16(a, bfrag, acc[mi], 0, 0, 0);
                }
            }
            __syncthreads();
        }

        // epilogue: shfl gate gather; c in LDS; h -> global
#pragma unroll
        for (int mi = 0; mi < 8; ++mi) {
#pragma unroll
            for (int r = 0; r < 4; ++r) {
                float v  = acc[mi][r] + bn;
                float vf = __shfl_xor(v, 4);
                float vg = __shfl_xor(v, 8);
                float vo = __shfl_xor(v, 12);
                if (l16 < 4) {
                    const int crow = mi * 16 + quad * 4 + r;
                    const float cn = sigm(vf) * c_lds[crow * 32 + ccol] + sigm(v) * tanh_fast(vg);
                    c_lds[crow * 32 + ccol] = cn;
                    hout[(size_t)(mb * 128 + crow) * H_DIM + unit] = f2bf(sigm(vo) * tanh_fast(cn));
                }
            }
        }
        __syncthreads();       // all waves' h stores drained (vmcnt0 at barrier)
        if (tid == 0) {
            __threadfence();   // release: write back h to device scope
            __hip_atomic_fetch_add(&cnt[t * 8 + mb], 1u,
                                   __ATOMIC_RELEASE, __HIP_MEMORY_SCOPE_AGENT);
        }
    }
#undef STAGE_A
}

// ---- final projection via MFMA (hi/lo split w_fc) ----
__global__ __launch_bounds__(256, 1)
void proj_mfma(const unsigned short* __restrict__ h,
               const unsigned short* __restrict__ whi,
               const unsigned short* __restrict__ wlo,
               const float* __restrict__ b_fc,
               float* __restrict__ out) {
    const int wm = threadIdx.x >> 6, lane = threadIdx.x & 63;
    const int quad = lane >> 4, l16 = lane & 15;
    const int m0 = blockIdx.x * 64 + wm * 16;

    f32x4 acc[4];
#pragma unroll
    for (int ni = 0; ni < 4; ni++) acc[ni] = f32x4{0.f, 0.f, 0.f, 0.f};

    for (int k0 = 0; k0 < H_DIM; k0 += 32) {
        bf16x8 a = *(const bf16x8*)&h[(size_t)(m0 + l16) * H_DIM + k0 + quad * 8];
#pragma unroll
        for (int ni = 0; ni < 4; ni++) {
            const size_t wi = (size_t)(ni * 16 + l16) * H_DIM + k0 + quad * 8;
            bf16x8 bh = *(const bf16x8*)&whi[wi];
            bf16x8 bl = *(const bf16x8*)&wlo[wi];
            acc[ni] = __builtin_amdgcn_mfma_f32_16x16x32_bf16(a, bh, acc[ni], 0, 0, 0);
            acc[ni] = __builtin_amdgcn_mfma_f32_16x16x32_bf16(a, bl, acc[ni], 0, 0, 0);
        }
    }
#pragma unroll
    for (int ni = 0; ni < 4; ni++) {
        const float bfc = b_fc[ni * 16 + l16];
#pragma unroll
        for (int r = 0; r < 4; r++) {
            out[(size_t)(m0 + quad * 4 + r) * O_DIM + ni * 16 + l16] = acc[ni][r] + bfc;
        }
    }
}

extern "C" void kernel_launch(void* const* d_in, const int* in_sizes, int n_in,
                              void* d_out, int out_size, void* d_ws, size_t ws_size,
                              hipStream_t stream) {
    const float* x    = (const float*)d_in[0];
    const float* w_ih = (const float*)d_in[1];
    const float* w_hh = (const float*)d_in[2];
    const float* b_ih = (const float*)d_in[3];
    const float* b_hh = (const float*)d_in[4];
    const float* w_fc = (const float*)d_in[5];
    const float* b_fc = (const float*)d_in[6];
    float* out = (float*)d_out;

    char* ws = (char*)d_ws;
    size_t off = 0;
    unsigned short* xb   = (unsigned short*)(ws + off); off += (size_t)B_DIM * XROW * 2;
    unsigned short* W2   = (unsigned short*)(ws + off); off += (size_t)NCHUNK * 131072 * 2;
    unsigned short* Wihg = (unsigned short*)(ws + off); off += (size_t)32 * 16384 * 2;
    float* bias2         = (float*)(ws + off);          off += (size_t)4 * H_DIM * 4;
    unsigned short* h0   = (unsigned short*)(ws + off); off += (size_t)B_DIM * H_DIM * 2;
    unsigned short* h1   = (unsigned short*)(ws + off); off += (size_t)B_DIM * H_DIM * 2;
    unsigned short* whi  = (unsigned short*)(ws + off); off += (size_t)O_DIM * H_DIM * 2;
    unsigned short* wlo  = (unsigned short*)(ws + off); off += (size_t)O_DIM * H_DIM * 2;
    unsigned int* cnt    = (unsigned int*)(ws + off);   off += (size_t)T_DIM * 8 * 4;

    conv_x<<<8192, 256, 0, stream>>>(x, xb);
    build_w2<<<4 * H_DIM, 256, 0, stream>>>(w_ih, w_hh, b_ih, b_hh, W2, bias2);
    build_wih<<<4 * H_DIM, 128, 0, stream>>>(w_ih, Wihg);
    conv_wfc<<<256, 256, 0, stream>>>(w_fc, whi, wlo);
    zero_hcnt<<<4096, 256, 0, stream>>>(h0, cnt);

    void* args[] = {(void*)&xb, (void*)&W2, (void*)&Wihg, (void*)&bias2,
                    (void*)&h0, (void*)&h1, (void*)&cnt};
    hipLaunchCooperativeKernel((void*)lstm_persist, dim3(8, 32), dim3(512),
                               args, 0, stream);

    // t=127 wrote h0
    proj_mfma<<<16, 256, 0, stream>>>(h0, whi, wlo, b_fc, out);
}

// Round 7
// 4519.398 us; speedup vs baseline: 1.9250x; 1.4867x over previous
//
#include <hip/hip_runtime.h>
#include <hip/hip_cooperative_groups.h>

// LSTM: B=1024, T=128, I=128, H=1024, O=64
// R6: persistent kernel, spin fixed.
//  - R5 post-mortem: the consumer spin used ACQUIRE agent loads -> one
//    buffer_inv PER POLL; ~32 spinning tid0s per XCD continuously nuked the
//    L2 other blocks were staging from (FETCH 626 MB = 30x ideal, 45us/step
//    stall). Now: RELAXED polls (scope->cpol keeps remote visibility,
//    ordering->no fence), ONE acquire __threadfence after loop exit.
//  - c_lds stride 32 -> 33: bank was ccol%32 (4-way x 64 ops/wave/step =
//    33.5M conflict cycles measured); now (crow+ccol)%32 = conflict-free.
// Carried: per-mb 32-block flag barrier (producer: threadfence + relaxed
// add), W_hh in 128 regs, W_ih in 32 KB LDS image, dbuf A-staging via
// global_load_lds(16B) w/ XOR swizzle, shfl gate gather, c in LDS,
// MFMA proj with hi/lo bf16 w_fc.

#define B_DIM 1024
#define H_DIM 1024
#define I_DIM 128
#define T_DIM 128
#define XROW  (T_DIM * I_DIM)   // 16384
#define NCHUNK 36               // total K chunks of 32 (x: 0..3, h: 4..35)
#define O_DIM 64

typedef float f32x4 __attribute__((ext_vector_type(4)));
typedef short bf16x8 __attribute__((ext_vector_type(8)));
typedef unsigned short u16x8 __attribute__((ext_vector_type(8)));

__device__ __forceinline__ unsigned short f2bf(float f) {
    union { float f; unsigned int u; } v; v.f = f;
    unsigned int r = v.u + 0x7fffu + ((v.u >> 16) & 1u);  // RNE
    return (unsigned short)(r >> 16);
}
__device__ __forceinline__ float bf2f(unsigned short b) {
    union { unsigned int u; float f; } v; v.u = ((unsigned int)b) << 16;
    return v.f;
}
__device__ __forceinline__ float sigm(float x) { return 1.f / (1.f + __expf(-x)); }
__device__ __forceinline__ float tanh_fast(float x) { return 2.f / (1.f + __expf(-2.f * x)) - 1.f; }

// ---- prep: fp32 x -> bf16 ----
__global__ void conv_x(const float* __restrict__ x, unsigned short* __restrict__ xb) {
    size_t i = ((size_t)blockIdx.x * 256 + threadIdx.x) * 8;
    float4 v0 = *(const float4*)(x + i);
    float4 v1 = *(const float4*)(x + i + 4);
    u16x8 o;
    o[0] = f2bf(v0.x); o[1] = f2bf(v0.y); o[2] = f2bf(v0.z); o[3] = f2bf(v0.w);
    o[4] = f2bf(v1.x); o[5] = f2bf(v1.y); o[6] = f2bf(v1.z); o[7] = f2bf(v1.w);
    *(u16x8*)(xb + i) = o;
}

// ---- prep: W2 in B-fragment order + combined bias ----
// N-order n: nb=n>>7, wn=(n>>4)&7, gate=(n>>2)&3, ju=n&3
//   -> orig gate row = gate*1024 + nb*32 + wn*4 + ju
__global__ void build_w2(const float* __restrict__ w_ih, const float* __restrict__ w_hh,
                         const float* __restrict__ b_ih, const float* __restrict__ b_hh,
                         unsigned short* __restrict__ W2, float* __restrict__ bias2) {
    int n = blockIdx.x;
    int nb = n >> 7, wn = (n >> 4) & 7, gate = (n >> 2) & 3, ju = n & 3;
    int orig = gate * 1024 + nb * 32 + wn * 4 + ju;
    for (int k = threadIdx.x; k < 1152; k += 256) {
        float v = (k < I_DIM) ? w_ih[(size_t)orig * I_DIM + k]
                              : w_hh[(size_t)orig * H_DIM + (k - I_DIM)];
        int cch = k >> 5, q = (k >> 3) & 3, j = k & 7;
        W2[(size_t)cch * 131072 + (size_t)n * 32 + q * 8 + j] = f2bf(v);
    }
    if (threadIdx.x == 0) bias2[n] = b_ih[orig] + b_hh[orig];
}

// ---- prep: W_ih LDS image per nb, swizzled (phys grp g holds logical g^(col&7)) ----
__global__ void build_wih(const float* __restrict__ w_ih,
                          unsigned short* __restrict__ Wihg) {
    int n = blockIdx.x;              // 0..4095 (N-order)
    int nb = n >> 7, col = n & 127;
    int wn = col >> 4, gate = (col >> 2) & 3, ju = col & 3;
    int orig = gate * 1024 + nb * 32 + wn * 4 + ju;
    int k = threadIdx.x;             // 0..127
    int half = k >> 6, kl = k & 63;
    int glog = kl >> 3, j = kl & 7;
    int gphys = glog ^ (col & 7);
    Wihg[(((size_t)nb * 2 + half) * 128 + col) * 64 + gphys * 8 + j] =
        f2bf(w_ih[(size_t)orig * I_DIM + k]);
}

// ---- prep: w_fc fp32 -> hi/lo bf16 pair ----
__global__ void conv_wfc(const float* __restrict__ w_fc,
                         unsigned short* __restrict__ whi,
                         unsigned short* __restrict__ wlo) {
    int i = blockIdx.x * 256 + threadIdx.x;
    float v = w_fc[i];
    unsigned short h = f2bf(v);
    whi[i] = h;
    wlo[i] = f2bf(v - bf2f(h));
}

__global__ void zero_hcnt(unsigned short* __restrict__ h0, unsigned int* __restrict__ cnt) {
    int idx = blockIdx.x * 256 + threadIdx.x;   // 4096 blocks -> 1048576
    h0[idx] = 0;
    if (idx < T_DIM * 8) cnt[idx] = 0;
}

// ---- persistent LSTM ----
// grid (8 mb, 32 nb) x 512 threads; 1 block/CU; mb-group = 32 blocks/XCD.
__global__ __launch_bounds__(512, 1)
void lstm_persist(const unsigned short* __restrict__ xb,
                  const unsigned short* __restrict__ W2,
                  const unsigned short* __restrict__ Wihg,
                  const float* __restrict__ bias2,
                  unsigned short* __restrict__ h0,
                  unsigned short* __restrict__ h1,
                  unsigned int* __restrict__ cnt) {
    __shared__ __align__(16) unsigned short As[2 * 2 * 128 * 64];  // 64 KB
    __shared__ __align__(16) unsigned short Wih[2 * 128 * 64];     // 32 KB
    __shared__ float c_lds[128 * 33];                              // 16.5 KB (pad: bank = (crow+ccol)%32)
    const int tid  = threadIdx.x;
    const int wv   = tid >> 6, lane = tid & 63;
    const int quad = lane >> 4, l16 = lane & 15;
    const int l7   = l16 & 7;
    const int mb   = blockIdx.x, nb = blockIdx.y;

    // zero block-private c state
    for (int i = tid; i < 128 * 33; i += 512) c_lds[i] = 0.f;

    // one-time: W_ih image -> LDS
#pragma unroll
    for (int i = 0; i < 4; ++i) {
        const unsigned short* src = Wihg + (size_t)nb * 16384 + (wv * 4 + i) * 512 + lane * 8;
        __builtin_amdgcn_global_load_lds(
            (const __attribute__((address_space(1))) void*)src,
            (__attribute__((address_space(3))) void*)(&Wih[(wv * 4 + i) * 512]),
            16, 0, 0);
    }

    // one-time: W_hh B-fragments (K chunks 4..35) -> 128 regs (VGPR or AGPR)
    bf16x8 Breg[32];
    {
        const size_t nbase = (size_t)(nb * 128 + wv * 16 + l16) * 32 + quad * 8;
#pragma unroll
        for (int cch = 0; cch < 32; ++cch)
            Breg[cch] = *(const bf16x8*)&W2[(size_t)(cch + 4) * 131072 + nbase];
    }
    const float bn = bias2[nb * 128 + wv * 16 + l16];

    // staging lane geometry
    const int arow = lane >> 3;             // 0..7 local row
    const int ag   = lane & 7;              // physical 16B group
    const int cperm = ((ag ^ arow) << 3);   // swizzled source col (bf16 units)

    const int unit   = nb * 32 + wv * 4 + (l16 & 3);   // global h-unit (epilogue)
    const int ccol   = wv * 4 + (l16 & 3);             // c_lds col
    const int wihcol = wv * 16 + l16;

#define STAGE_A(SRCBASE, ROWSTRIDE, COLOFF, BUF)                                   \
    do {                                                                           \
        _Pragma("unroll")                                                          \
        for (int c4 = 0; c4 < 2; ++c4) {                                           \
            _Pragma("unroll")                                                      \
            for (int hf = 0; hf < 2; ++hf) {                                       \
                const int row0 = wv * 16 + c4 * 8;                                 \
                const unsigned short* src =                                        \
                    (SRCBASE) + (size_t)(mb * 128 + row0 + arow) * (ROWSTRIDE)     \
                              + (COLOFF) + hf * 64 + cperm;                        \
                __builtin_amdgcn_global_load_lds(                                  \
                    (const __attribute__((address_space(1))) void*)src,            \
                    (__attribute__((address_space(3))) void*)                      \
                        (&As[(((BUF) * 2 + hf) * 128 + row0) * 64]),               \
                    16, 0, 0);                                                     \
            }                                                                      \
        }                                                                          \
    } while (0)

    for (int t = 0; t < T_DIM; ++t) {
        const unsigned short* hin = (t & 1) ? h1 : h0;
        unsigned short* hout      = (t & 1) ? h0 : h1;

        f32x4 acc[8];
#pragma unroll
        for (int mi = 0; mi < 8; ++mi) acc[mi] = f32x4{0.f, 0.f, 0.f, 0.f};

        // stage seg0 (x_t) into buf0; overlap with the group-barrier spin
        STAGE_A(xb, XROW, t * I_DIM, 0);
        if (t > 0 && tid == 0) {
            // RELAXED polls: no per-iteration cache invalidate. Scope (agent)
            // sets the load's coherence bits, so remote atomicAdds are seen.
            while (__hip_atomic_load(&cnt[(t - 1) * 8 + mb],
                                     __ATOMIC_RELAXED, __HIP_MEMORY_SCOPE_AGENT) < 32u)
                __builtin_amdgcn_s_sleep(1);
            __threadfence();   // ONE acquire fence: invalidate stale h lines
        }
        __syncthreads();       // seg0 resident + spin done + Wih (t==0)

        // seg 0: B-fragments from Wih LDS; prefetch seg1
        STAGE_A(hin, H_DIM, 0, 1);
#pragma unroll
        for (int cc = 0; cc < 4; ++cc) {
            const int half = cc >> 1, gb = (cc & 1) * 4;
            const int poff = (((gb + quad) ^ l7) << 3);
            bf16x8 bfrag = *(const bf16x8*)&Wih[(half * 128 + wihcol) * 64 + poff];
#pragma unroll
            for (int mi = 0; mi < 8; ++mi) {
                bf16x8 a = *(const bf16x8*)&As[((0 * 2 + half) * 128 + mi * 16 + l16) * 64 + poff];
                acc[mi] = __builtin_amdgcn_mfma_f32_16x16x32_bf16(a, bfrag, acc[mi], 0, 0, 0);
            }
        }
        __syncthreads();

        // segs 1..8: B-fragments from Breg
#pragma unroll
        for (int sg = 1; sg <= 8; ++sg) {
            if (sg < 8) STAGE_A(hin, H_DIM, sg * 128, (sg + 1) & 1);
            const int bufc = sg & 1;
#pragma unroll
            for (int cc = 0; cc < 4; ++cc) {
                const int half = cc >> 1, gb = (cc & 1) * 4;
                const int poff = (((gb + quad) ^ l7) << 3);
                bf16x8 bfrag = Breg[(sg - 1) * 4 + cc];
#pragma unroll
                for (int mi = 0; mi < 8; ++mi) {
                    bf16x8 a = *(const bf16x8*)&As[((bufc * 2 + half) * 128 + mi * 16 + l16) * 64 + poff];
                    acc[mi] = __builtin_amdgcn_mfma_f32_16x16x32_bf16(a, bfrag, acc[mi], 0, 0, 0);
                }
            }
            __syncthreads();
        }

        // epilogue: shfl gate gather; c in LDS (padded); h -> global
#pragma unroll
        for (int mi = 0; mi < 8; ++mi) {
#pragma unroll
            for (int r = 0; r < 4; ++r) {
                float v  = acc[mi][r] + bn;
                float vf = __shfl_xor(v, 4);
                float vg = __shfl_xor(v, 8);
                float vo = __shfl_xor(v, 12);
                if (l16 < 4) {
                    const int crow = mi * 16 + quad * 4 + r;
                    const float cn = sigm(vf) * c_lds[crow * 33 + ccol] + sigm(v) * tanh_fast(vg);
                    c_lds[crow * 33 + ccol] = cn;
                    hout[(size_t)(mb * 128 + crow) * H_DIM + unit] = f2bf(sigm(vo) * tanh_fast(cn));
                }
            }
        }
        __syncthreads();       // all waves' h stores drained (vmcnt0 at barrier)
        if (tid == 0) {
            __threadfence();   // release: L2 writeback of this block's h slice
            __hip_atomic_fetch_add(&cnt[t * 8 + mb], 1u,
                                   __ATOMIC_RELAXED, __HIP_MEMORY_SCOPE_AGENT);
        }
    }
#undef STAGE_A
}

// ---- final projection via MFMA (hi/lo split w_fc) ----
__global__ __launch_bounds__(256, 1)
void proj_mfma(const unsigned short* __restrict__ h,
               const unsigned short* __restrict__ whi,
               const unsigned short* __restrict__ wlo,
               const float* __restrict__ b_fc,
               float* __restrict__ out) {
    const int wm = threadIdx.x >> 6, lane = threadIdx.x & 63;
    const int quad = lane >> 4, l16 = lane & 15;
    const int m0 = blockIdx.x * 64 + wm * 16;

    f32x4 acc[4];
#pragma unroll
    for (int ni = 0; ni < 4; ni++) acc[ni] = f32x4{0.f, 0.f, 0.f, 0.f};

    for (int k0 = 0; k0 < H_DIM; k0 += 32) {
        bf16x8 a = *(const bf16x8*)&h[(size_t)(m0 + l16) * H_DIM + k0 + quad * 8];
#pragma unroll
        for (int ni = 0; ni < 4; ni++) {
            const size_t wi = (size_t)(ni * 16 + l16) * H_DIM + k0 + quad * 8;
            bf16x8 bh = *(const bf16x8*)&whi[wi];
            bf16x8 bl = *(const bf16x8*)&wlo[wi];
            acc[ni] = __builtin_amdgcn_mfma_f32_16x16x32_bf16(a, bh, acc[ni], 0, 0, 0);
            acc[ni] = __builtin_amdgcn_mfma_f32_16x16x32_bf16(a, bl, acc[ni], 0, 0, 0);
        }
    }
#pragma unroll
    for (int ni = 0; ni < 4; ni++) {
        const float bfc = b_fc[ni * 16 + l16];
#pragma unroll
        for (int r = 0; r < 4; r++) {
            out[(size_t)(m0 + quad * 4 + r) * O_DIM + ni * 16 + l16] = acc[ni][r] + bfc;
        }
    }
}

extern "C" void kernel_launch(void* const* d_in, const int* in_sizes, int n_in,
                              void* d_out, int out_size, void* d_ws, size_t ws_size,
                              hipStream_t stream) {
    const float* x    = (const float*)d_in[0];
    const float* w_ih = (const float*)d_in[1];
    const float* w_hh = (const float*)d_in[2];
    const float* b_ih = (const float*)d_in[3];
    const float* b_hh = (const float*)d_in[4];
    const float* w_fc = (const float*)d_in[5];
    const float* b_fc = (const float*)d_in[6];
    float* out = (float*)d_out;

    char* ws = (char*)d_ws;
    size_t off = 0;
    unsigned short* xb   = (unsigned short*)(ws + off); off += (size_t)B_DIM * XROW * 2;
    unsigned short* W2   = (unsigned short*)(ws + off); off += (size_t)NCHUNK * 131072 * 2;
    unsigned short* Wihg = (unsigned short*)(ws + off); off += (size_t)32 * 16384 * 2;
    float* bias2         = (float*)(ws + off);          off += (size_t)4 * H_DIM * 4;
    unsigned short* h0   = (unsigned short*)(ws + off); off += (size_t)B_DIM * H_DIM * 2;
    unsigned short* h1   = (unsigned short*)(ws + off); off += (size_t)B_DIM * H_DIM * 2;
    unsigned short* whi  = (unsigned short*)(ws + off); off += (size_t)O_DIM * H_DIM * 2;
    unsigned short* wlo  = (unsigned short*)(ws + off); off += (size_t)O_DIM * H_DIM * 2;
    unsigned int* cnt    = (unsigned int*)(ws + off);   off += (size_t)T_DIM * 8 * 4;

    conv_x<<<8192, 256, 0, stream>>>(x, xb);
    build_w2<<<4 * H_DIM, 256, 0, stream>>>(w_ih, w_hh, b_ih, b_hh, W2, bias2);
    build_wih<<<4 * H_DIM, 128, 0, stream>>>(w_ih, Wihg);
    conv_wfc<<<256, 256, 0, stream>>>(w_fc, whi, wlo);
    zero_hcnt<<<4096, 256, 0, stream>>>(h0, cnt);

    void* args[] = {(void*)&xb, (void*)&W2, (void*)&Wihg, (void*)&bias2,
                    (void*)&h0, (void*)&h1, (void*)&cnt};
    hipLaunchCooperativeKernel((void*)lstm_persist, dim3(8, 32), dim3(512),
                               args, 0, stream);

    // t=127 wrote h0
    proj_mfma<<<16, 256, 0, stream>>>(h0, whi, wlo, b_fc, out);
}